// Round 6
// baseline (221.866 us; speedup 1.0000x reference)
//
#include <hip/hip_runtime.h>

#define B_   256
#define I_   1152
#define N_   10
#define P_   9216      // 8 * 1152
#define NO_  160       // 10 * 16
#define NBLK 640

typedef unsigned short u16;
typedef short s8v __attribute__((ext_vector_type(8)));
typedef float f4v __attribute__((ext_vector_type(4)));

__device__ inline float bf2f(u16 u){
  unsigned v = ((unsigned)u) << 16; float f; __builtin_memcpy(&f, &v, 4); return f;
}
__device__ inline u16 f2bf(float f){
  unsigned b; __builtin_memcpy(&b, &f, 4);
  b += 0x7fffu + ((b >> 16) & 1u);   // RNE
  return (u16)(b >> 16);
}
// MALL-coherent accessors (bypass L1/L2; atomic-produced data lives at MALL)
__device__ inline void ald2(const float* p, float& a, float& b){
  unsigned long long q = __hip_atomic_load((const unsigned long long*)p,
      __ATOMIC_RELAXED, __HIP_MEMORY_SCOPE_AGENT);
  unsigned lo = (unsigned)q, hi = (unsigned)(q >> 32);
  __builtin_memcpy(&a, &lo, 4); __builtin_memcpy(&b, &hi, 4);
}
__device__ inline float ald1(const float* p){
  unsigned u = __hip_atomic_load((const unsigned*)p,
      __ATOMIC_RELAXED, __HIP_MEMORY_SCOPE_AGENT);
  float f; __builtin_memcpy(&f, &u, 4); return f;
}
__device__ inline void ast1(float* p, float v){
  unsigned u; __builtin_memcpy(&u, &v, 4);
  __hip_atomic_store((unsigned*)p, u, __ATOMIC_RELAXED, __HIP_MEMORY_SCOPE_AGENT);
}
__device__ inline void astu(unsigned* p, unsigned v){
  __hip_atomic_store(p, v, __ATOMIC_RELAXED, __HIP_MEMORY_SCOPE_AGENT);
}

// c LDS swizzle: element j stored at CIX(j); reader at 10m..10m+7 gets j=8m..8m+7
#define CIX(j) ((j) + (((j) >> 3) << 1))

// ---------------------------------------------------------------------------
// k_prep: 2913 blocks x 128.
//  [0,1440):   W -> Wt bf16 (LDS transpose, uint4 stores)
//  [1440,2592): x -> xbp + xpb (LDS transpose, uint4 stores)
//  [2592,2912): zero sA
//  2912:        zero bar (4128 ints; includes vflag)
__global__ __launch_bounds__(128) void k_prep(
    const float* __restrict__ x, const float* __restrict__ W,
    u16* __restrict__ xbp, u16* __restrict__ xpb, u16* __restrict__ Wt,
    float* __restrict__ sA, int* __restrict__ bar){
  __shared__ union { u16 w[8][136]; float t[32][68]; } sm;
  int t = threadIdx.x, u = blockIdx.x;
  if (u < 1440){
    int q = u/9, ch = u - q*9;
    int n = q >> 4, o = q & 15;
    int i = ch*128 + t;
    const float* src = W + (size_t)i*1280 + n*128 + o*8;
    float4 a = *reinterpret_cast<const float4*>(src);
    float4 b = *reinterpret_cast<const float4*>(src + 4);
    float vv[8] = {a.x,a.y,a.z,a.w,b.x,b.y,b.z,b.w};
    #pragma unroll
    for (int k = 0; k < 8; ++k) sm.w[k][t] = f2bf(vv[k] * 0.03f);
    __syncthreads();
    int k = t >> 4, seg = t & 15;
    uint4 val = *reinterpret_cast<const uint4*>(&sm.w[k][seg*8]);
    *reinterpret_cast<uint4*>(Wt + (size_t)q*P_ + (size_t)k*I_ + ch*128 + seg*8) = val;
  } else if (u < 2592){
    int v = u - 1440;
    int tb = v/144, tp = v - tb*144;
    int b0 = tb*32, p0 = tp*64;
    #pragma unroll
    for (int pass = 0; pass < 2; ++pass){
      int vt = t + (pass << 7);
      int r = vt >> 3, c8 = (vt & 7)*8;
      const float* sp = x + (size_t)(b0 + r)*P_ + p0 + c8;
      float4 a = *reinterpret_cast<const float4*>(sp);
      float4 b = *reinterpret_cast<const float4*>(sp + 4);
      *reinterpret_cast<float4*>(&sm.t[r][c8]) = a;
      *reinterpret_cast<float4*>(&sm.t[r][c8+4]) = b;
      uint4 pk;
      pk.x = (unsigned)f2bf(a.x) | ((unsigned)f2bf(a.y) << 16);
      pk.y = (unsigned)f2bf(a.z) | ((unsigned)f2bf(a.w) << 16);
      pk.z = (unsigned)f2bf(b.x) | ((unsigned)f2bf(b.y) << 16);
      pk.w = (unsigned)f2bf(b.z) | ((unsigned)f2bf(b.w) << 16);
      *reinterpret_cast<uint4*>(xbp + (size_t)(b0 + r)*P_ + p0 + c8) = pk;
    }
    __syncthreads();
    #pragma unroll
    for (int pass = 0; pass < 2; ++pass){
      int vt = t + (pass << 7);
      int pc = vt >> 2, rb = (vt & 3)*8;
      uint4 pk;
      pk.x = (unsigned)f2bf(sm.t[rb+0][pc]) | ((unsigned)f2bf(sm.t[rb+1][pc]) << 16);
      pk.y = (unsigned)f2bf(sm.t[rb+2][pc]) | ((unsigned)f2bf(sm.t[rb+3][pc]) << 16);
      pk.z = (unsigned)f2bf(sm.t[rb+4][pc]) | ((unsigned)f2bf(sm.t[rb+5][pc]) << 16);
      pk.w = (unsigned)f2bf(sm.t[rb+6][pc]) | ((unsigned)f2bf(sm.t[rb+7][pc]) << 16);
      *reinterpret_cast<uint4*>(xpb + (size_t)(p0 + pc)*B_ + b0 + rb) = pk;
    }
  } else if (u < 2912){
    sA[(u - 2592)*128 + t] = 0.f;
  } else {
    for (int z = t; z < 4128; z += 128) bar[z] = 0;
  }
}

// ---------------------------------------------------------------------------
// Fence-free monotonic grid barrier, 640 arrivals: 64 leaves x 10 -> root(64)
// -> 64 padded release words. RELAXED agent atomics only (no cache
// maintenance); __syncthreads before arrival drains vmcnt.
// bar: leaf li @ [li*32]; rel li @ [2048+li*32]; root @ [4096]; vflag @ [4100].
__device__ inline void gbar(int* bar, int bid, int ph){
  __syncthreads();
  if (threadIdx.x == 0){
    int li = bid & 63;
    if (__hip_atomic_fetch_add(bar + li*32, 1, __ATOMIC_RELAXED,
                               __HIP_MEMORY_SCOPE_AGENT) == ph*10 - 1){
      if (__hip_atomic_fetch_add(bar + 4096, 1, __ATOMIC_RELAXED,
                                 __HIP_MEMORY_SCOPE_AGENT) == ph*64 - 1){
        #pragma unroll
        for (int z = 0; z < 64; ++z)
          __hip_atomic_store(bar + 2048 + z*32, ph, __ATOMIC_RELAXED,
                             __HIP_MEMORY_SCOPE_AGENT);
      }
    }
    while (__hip_atomic_load(bar + 2048 + li*32, __ATOMIC_RELAXED,
                             __HIP_MEMORY_SCOPE_AGENT) < ph)
      __builtin_amdgcn_s_sleep(4);
  }
  __syncthreads();
}

// ---------------------------------------------------------------------------
union LdsU {
  struct { float c[720]; u16 Bt[16][592]; } S;   // 2880 + 18944 = 21824 B
  struct { float bijL[16][10]; } G;              // 640 B
};

// ---------------------------------------------------------------------------
// V (bids 72..81) || G' (bids 0..71).
// V: squash s -> vbt bf16 [n*16+o][b] (MALL stores), bump vflag.
// G': per i-tile of 16: all 8 k u-tiles x all 10 n, MFMA over b (vbt from
// global, L2), Wt-weight + o-reduce -> LDS accumulate over k -> bij in
// REGISTERS (block persists across phases) -> softmax -> cT (MALL stores).
__device__ inline void phase_VG(int t, int bid,
    const u16* __restrict__ xpb, const u16* __restrict__ Wt,
    const float* __restrict__ s, u16* __restrict__ vbt,
    float* __restrict__ cT, int* __restrict__ bar, int vthr,
    float* bijr, LdsU* lds)
{
  if (bid >= 72 && bid < 82){
    int n = bid - 72, bp = t, b0 = bp*2;
    const float* s0p = s + (size_t)b0*NO_ + n*16;
    const float* s1p = s0p + NO_;
    float v0[16], v1[16];
    #pragma unroll
    for (int k = 0; k < 8; ++k){
      ald2(s0p + 2*k, v0[2*k], v0[2*k+1]);
      ald2(s1p + 2*k, v1[2*k], v1[2*k+1]);
    }
    float sq0 = 0.f, sq1 = 0.f;
    #pragma unroll
    for (int o = 0; o < 16; ++o){ sq0 += v0[o]*v0[o]; sq1 += v1[o]*v1[o]; }
    float sc0 = sqrtf(sq0)/(1.0f + sq0), sc1 = sqrtf(sq1)/(1.0f + sq1);
    unsigned* vb32 = reinterpret_cast<unsigned*>(vbt);
    #pragma unroll
    for (int o = 0; o < 16; ++o){
      unsigned pk = (unsigned)f2bf(v0[o]*sc0) | ((unsigned)f2bf(v1[o]*sc1) << 16);
      astu(&vb32[(n*16 + o)*128 + bp], pk);
    }
    __syncthreads();
    if (t == 0)
      __hip_atomic_fetch_add(bar + 4100, 1, __ATOMIC_RELAXED, __HIP_MEMORY_SCOPE_AGENT);
  } else if (bid < 72){
    // FIX (R5 bug): zero ALL 160 floats of bijL (128 threads -> strided loop;
    // the R5 `if (t<160)` left elements 128..159 = rows 12..15 as stale LDS
    // garbage, corrupting b_ij for a quarter of every i-tile).
    for (int z = t; z < 160; z += 128)
      reinterpret_cast<float*>(lds->G.bijL)[z] = 0.f;
    if (t == 0){
      while (__hip_atomic_load(bar + 4100, __ATOMIC_RELAXED,
                               __HIP_MEMORY_SCOPE_AGENT) < vthr)
        __builtin_amdgcn_s_sleep(2);
    }
    __syncthreads();
    int wv = t >> 6, l = t & 63, lo = l & 15, quad = l >> 4;
    int i0 = bid*16;
    #pragma unroll
    for (int kk = 0; kk < 4; ++kk){
      int k = wv*4 + kk;
      int p0 = k*1152 + i0;
      const s8v* ap = reinterpret_cast<const s8v*>(xpb + (size_t)(p0 + lo)*B_ + quad*8);
      #pragma unroll
      for (int np = 0; np < 5; ++np){
        int n0 = np*2;
        const s8v* b0p = reinterpret_cast<const s8v*>(vbt + (size_t)(n0*16 + lo)*B_ + quad*8);
        const s8v* b1p = reinterpret_cast<const s8v*>(vbt + (size_t)((n0+1)*16 + lo)*B_ + quad*8);
        f4v acc0 = {0.f,0.f,0.f,0.f}, acc1 = {0.f,0.f,0.f,0.f};
        #pragma unroll
        for (int st = 0; st < 8; ++st){
          s8v a = ap[4*st];
          acc0 = __builtin_amdgcn_mfma_f32_16x16x32_bf16(a, b0p[4*st], acc0, 0, 0, 0);
          acc1 = __builtin_amdgcn_mfma_f32_16x16x32_bf16(a, b1p[4*st], acc1, 0, 0, 0);
        }
        #pragma unroll
        for (int sb = 0; sb < 2; ++sb){
          f4v acc = sb ? acc1 : acc0;
          int n = n0 + sb;
          ushort4 w4 = *reinterpret_cast<const ushort4*>(
              Wt + (size_t)(n*16 + lo)*P_ + p0 + quad*4);
          float v0 = acc[0]*bf2f(w4.x), v1 = acc[1]*bf2f(w4.y);
          float v2 = acc[2]*bf2f(w4.z), v3 = acc[3]*bf2f(w4.w);
          #pragma unroll
          for (int m = 8; m >= 1; m >>= 1){
            v0 += __shfl_xor(v0, m, 16);
            v1 += __shfl_xor(v1, m, 16);
            v2 += __shfl_xor(v2, m, 16);
            v3 += __shfl_xor(v3, m, 16);
          }
          if (lo == 0){
            int r0 = quad*4;
            atomicAdd(&lds->G.bijL[r0+0][n], v0 * (1.f/256.f));
            atomicAdd(&lds->G.bijL[r0+1][n], v1 * (1.f/256.f));
            atomicAdd(&lds->G.bijL[r0+2][n], v2 * (1.f/256.f));
            atomicAdd(&lds->G.bijL[r0+3][n], v3 * (1.f/256.f));
          }
        }
      }
    }
    __syncthreads();
    if (t < 16){
      float e[10]; float mx = -1e30f;
      #pragma unroll
      for (int j = 0; j < 10; ++j){
        bijr[j] += lds->G.bijL[t][j];
        mx = fmaxf(mx, bijr[j]);
      }
      float se = 0.f;
      #pragma unroll
      for (int j = 0; j < 10; ++j){ e[j] = __expf(bijr[j] - mx); se += e[j]; }
      float inv = 1.0f / se;
      #pragma unroll
      for (int j = 0; j < 10; ++j)
        ast1(&cT[(size_t)j*I_ + i0 + t], e[j] * inv);
    }
  }
}

// ---------------------------------------------------------------------------
// S phase: kc = bid&7 owns K-chunk of 1152 p (one k-slice; c index == p_loc),
// processed as 2 halves of 576 through the 16x592 Bt. 328K atomics (8/addr).
__device__ inline void phase_S(int t, int bid,
    const u16* __restrict__ xbp, const u16* __restrict__ Wt,
    const float* __restrict__ cT, float* __restrict__ s_cur,
    float* __restrict__ s_zero, LdsU* lds)
{
  int kc = bid & 7, rest = bid >> 3;
  int n = rest % 10, bx2 = rest / 10;
  if (s_zero && t < 64) ast1(&s_zero[bid*64 + t], 0.f);
  int wid = t >> 6, l = t & 63, lo = l & 15, quad = l >> 4;
  int b0 = bx2*32 + wid*16;
  f4v acc0 = {0.f,0.f,0.f,0.f}, acc1 = {0.f,0.f,0.f,0.f};

  #pragma unroll
  for (int h2 = 0; h2 < 2; ++h2){
    int off = kc*1152 + h2*576;
    const float* cp = cT + (size_t)n*I_ + h2*576;
    __syncthreads();                       // protect prev half's Bt/c reads
    {
      float4 v = *reinterpret_cast<const float4*>(cp + 4*t);
      int d = CIX(4*t);
      lds->S.c[d] = v.x; lds->S.c[d+1] = v.y; lds->S.c[d+2] = v.z; lds->S.c[d+3] = v.w;
      if (t < 16){
        float4 w = *reinterpret_cast<const float4*>(cp + 512 + 4*t);
        int d2 = CIX(512 + 4*t);
        lds->S.c[d2] = w.x; lds->S.c[d2+1] = w.y; lds->S.c[d2+2] = w.z; lds->S.c[d2+3] = w.w;
      }
    }
    __syncthreads();
    #pragma unroll
    for (int s9 = 0; s9 < 9; ++s9){
      int uu = t + s9*128;
      int r = uu / 72, m = uu - r*72;
      uint4 w = *reinterpret_cast<const uint4*>(Wt + (size_t)(n*16 + r)*P_ + off + m*8);
      const float* cc = &lds->S.c[10*m];
      float2 ca = *reinterpret_cast<const float2*>(cc);
      float2 cb = *reinterpret_cast<const float2*>(cc + 2);
      float2 cd = *reinterpret_cast<const float2*>(cc + 4);
      float2 ce = *reinterpret_cast<const float2*>(cc + 6);
      uint4 rr;
      rr.x = (unsigned)f2bf(bf2f(w.x & 0xffff)*ca.x) | ((unsigned)f2bf(bf2f(w.x >> 16)*ca.y) << 16);
      rr.y = (unsigned)f2bf(bf2f(w.y & 0xffff)*cb.x) | ((unsigned)f2bf(bf2f(w.y >> 16)*cb.y) << 16);
      rr.z = (unsigned)f2bf(bf2f(w.z & 0xffff)*cd.x) | ((unsigned)f2bf(bf2f(w.z >> 16)*cd.y) << 16);
      rr.w = (unsigned)f2bf(bf2f(w.w & 0xffff)*ce.x) | ((unsigned)f2bf(bf2f(w.w >> 16)*ce.y) << 16);
      *reinterpret_cast<uint4*>(&lds->S.Bt[r][m*8]) = rr;
    }
    __syncthreads();
    const s8v* ap = reinterpret_cast<const s8v*>(xbp + (size_t)(b0 + lo)*P_ + off + quad*8);
    #pragma unroll
    for (int s = 0; s < 9; ++s){
      s8v a0 = ap[8*s];
      s8v b0v = *reinterpret_cast<const s8v*>(&lds->S.Bt[lo][quad*8 + 64*s]);
      s8v a1 = ap[8*s + 4];
      s8v b1v = *reinterpret_cast<const s8v*>(&lds->S.Bt[lo][quad*8 + 64*s + 32]);
      acc0 = __builtin_amdgcn_mfma_f32_16x16x32_bf16(a0, b0v, acc0, 0, 0, 0);
      acc1 = __builtin_amdgcn_mfma_f32_16x16x32_bf16(a1, b1v, acc1, 0, 0, 0);
    }
  }
  f4v acc = acc0 + acc1;
  int r0 = quad << 2;
  #pragma unroll
  for (int r = 0; r < 4; ++r)
    atomicAdd(&s_cur[(size_t)(b0 + r0 + r)*NO_ + n*16 + lo], acc[r]);
}

__global__ __launch_bounds__(128, 2) void k_route(
    const u16* __restrict__ xbp, const u16* __restrict__ xpb,
    const u16* __restrict__ Wt,
    float* __restrict__ cTa, float* __restrict__ cTb,
    u16* __restrict__ vbtA, u16* __restrict__ vbtB,
    float* __restrict__ sA, float* __restrict__ sB,
    float* __restrict__ out, int* __restrict__ bar)
{
  __shared__ LdsU lds;
  int t = threadIdx.x, bid = blockIdx.x;
  float bijr[10];
  #pragma unroll
  for (int j = 0; j < 10; ++j) bijr[j] = 0.f;

  // ---- iter0 S: c == 0.1 uniform -> s = 0.1*(x . Wt^T), raw Wt B-frags,
  // full K=1152 per block (kc = bid&7). Zeroes sB.
  {
    int kc = bid & 7, rest = bid >> 3;
    int n = rest % 10, bx2 = rest / 10;
    if (t < 64) ast1(&sB[bid*64 + t], 0.f);
    int wid = t >> 6, l = t & 63, lo = l & 15, quad = l >> 4;
    int b0 = bx2*32 + wid*16;
    const s8v* ap = reinterpret_cast<const s8v*>(xbp + (size_t)(b0 + lo)*P_ + kc*1152 + quad*8);
    const s8v* bp = reinterpret_cast<const s8v*>(Wt  + (size_t)(n*16 + lo)*P_ + kc*1152 + quad*8);
    f4v acc0 = {0.f,0.f,0.f,0.f}, acc1 = {0.f,0.f,0.f,0.f};
    #pragma unroll
    for (int s = 0; s < 18; ++s){
      acc0 = __builtin_amdgcn_mfma_f32_16x16x32_bf16(ap[8*s],     bp[8*s],     acc0, 0, 0, 0);
      acc1 = __builtin_amdgcn_mfma_f32_16x16x32_bf16(ap[8*s + 4], bp[8*s + 4], acc1, 0, 0, 0);
    }
    f4v acc = acc0 + acc1;
    int r0 = quad << 2;
    #pragma unroll
    for (int r = 0; r < 4; ++r)
      atomicAdd(&sA[(size_t)(b0 + r0 + r)*NO_ + n*16 + lo], acc[r] * 0.1f);
  }
  gbar(bar, bid, 1);

  phase_VG(t, bid, xpb, Wt, sA, vbtA, cTa, bar, 10, bijr, &lds);  // V0 || G'0
  gbar(bar, bid, 2);

  phase_S(t, bid, xbp, Wt, cTa, sB, sA, &lds);                    // iter1 -> sB
  gbar(bar, bid, 3);

  phase_VG(t, bid, xpb, Wt, sB, vbtB, cTb, bar, 20, bijr, &lds);  // V1 || G'1
  gbar(bar, bid, 4);

  phase_S(t, bid, xbp, Wt, cTb, sA, nullptr, &lds);               // iter2 -> sA
  gbar(bar, bid, 5);

  // ---- final squash -> out (2560 rows of 16; first 320 blocks)
  if (bid < 320){
    int o = t & 15, rl = t >> 4;
    int rowid = bid*8 + rl;               // b*10+n
    int b = rowid / 10, n = rowid - b*10;
    size_t idx = (size_t)b*NO_ + n*16 + o;
    float sv = ald1(&sA[idx]);
    float sq = sv * sv;
    #pragma unroll
    for (int m = 8; m >= 1; m >>= 1) sq += __shfl_xor(sq, m, 16);
    out[idx] = sv * sqrtf(sq) / (1.0f + sq);
  }
}

// ---------------------------------------------------------------------------
extern "C" void kernel_launch(void* const* d_in, const int* in_sizes, int n_in,
                              void* d_out, int out_size, void* d_ws, size_t ws_size,
                              hipStream_t stream){
  (void)in_sizes; (void)n_in; (void)out_size; (void)ws_size;
  const float* x = (const float*)d_in[0];   // (256, 8, 1152)
  const float* W = (const float*)d_in[1];   // (1, 1152, 10, 16, 8)
  float* out = (float*)d_out;               // (256, 10, 16, 1) fp32

  float* sA  = (float*)d_ws;                // 40960 fp32
  float* sB  = sA + 40960;                  // 40960
  float* cTa = sB + 40960;                  // 11520 (10 x 1152)
  float* cTb = cTa + 11520;                 // 11520
  u16* vbtA = (u16*)(cTb + 11520);          // 40960 bf16 (160 x 256)
  u16* vbtB = vbtA + 40960;                 // 40960
  u16* xbp = vbtB + 40960;                  // 2359296 bf16
  u16* xpb = xbp + 2359296;                 // 2359296
  u16* Wt  = xpb + 2359296;                 // 1474560
  int* bar = (int*)(Wt + 1474560);          // 4128 ints (barrier + vflag)

  k_prep <<<2913, 128, 0, stream>>>(x, W, xbp, xpb, Wt, sA, bar);
  k_route<<<NBLK, 128, 0, stream>>>(xbp, xpb, Wt, cTa, cTb, vbtA, vbtB,
                                    sA, sB, out, bar);
}

// Round 7
// 151.858 us; speedup vs baseline: 1.4610x; 1.4610x over previous
//
#include <hip/hip_runtime.h>

#define B_   256
#define I_   1152
#define N_   10
#define P_   9216      // 8 * 1152
#define NO_  160       // 10 * 16
#define BIJS 12        // padded bij row stride (floats) -> 48B rows, 16B aligned
#define NBLK 1280

typedef unsigned short u16;
typedef short s8v __attribute__((ext_vector_type(8)));
typedef float f4v __attribute__((ext_vector_type(4)));

__device__ inline float bf2f(u16 u){
  unsigned v = ((unsigned)u) << 16; float f; __builtin_memcpy(&f, &v, 4); return f;
}
__device__ inline u16 f2bf(float f){
  unsigned b; __builtin_memcpy(&b, &f, 4);
  b += 0x7fffu + ((b >> 16) & 1u);   // RNE
  return (u16)(b >> 16);
}
// MALL-coherent scalar accessors (bypass L1/L2; atomic-produced data lives at MALL)
__device__ inline float ald1(const float* p){
  unsigned u = __hip_atomic_load((const unsigned*)p,
      __ATOMIC_RELAXED, __HIP_MEMORY_SCOPE_AGENT);
  float f; __builtin_memcpy(&f, &u, 4); return f;
}
__device__ inline void ast1(float* p, float v){
  unsigned u; __builtin_memcpy(&u, &v, 4);
  __hip_atomic_store((unsigned*)p, u, __ATOMIC_RELAXED, __HIP_MEMORY_SCOPE_AGENT);
}

// c LDS swizzle: element j stored at CIX(j); reader at 10m..10m+7 gets j=8m..8m+7
#define CIX(j) ((j) + (((j) >> 3) << 1))

// ---------------------------------------------------------------------------
// k_prep (R4-proven): 3021 blocks x 128.
//  [0,1440):   W -> Wt bf16 (LDS transpose, uint4 stores)
//  [1440,2592): x -> xbp + xpb (LDS transpose, uint4 stores)
//  [2592,2700): zero bij (13824 fl, stride-12 rows)
//  [2700,3020): zero sA
//  3020:        zero bar (4128 ints; includes cflag)
__global__ __launch_bounds__(128) void k_prep(
    const float* __restrict__ x, const float* __restrict__ W,
    u16* __restrict__ xbp, u16* __restrict__ xpb, u16* __restrict__ Wt,
    float* __restrict__ bij, float* __restrict__ sA, int* __restrict__ bar){
  __shared__ union { u16 w[8][136]; float t[32][68]; } sm;
  int t = threadIdx.x, u = blockIdx.x;
  if (u < 1440){
    int q = u/9, ch = u - q*9;
    int n = q >> 4, o = q & 15;
    int i = ch*128 + t;
    const float* src = W + (size_t)i*1280 + n*128 + o*8;
    float4 a = *reinterpret_cast<const float4*>(src);
    float4 b = *reinterpret_cast<const float4*>(src + 4);
    float vv[8] = {a.x,a.y,a.z,a.w,b.x,b.y,b.z,b.w};
    #pragma unroll
    for (int k = 0; k < 8; ++k) sm.w[k][t] = f2bf(vv[k] * 0.03f);
    __syncthreads();
    int k = t >> 4, seg = t & 15;
    uint4 val = *reinterpret_cast<const uint4*>(&sm.w[k][seg*8]);
    *reinterpret_cast<uint4*>(Wt + (size_t)q*P_ + (size_t)k*I_ + ch*128 + seg*8) = val;
  } else if (u < 2592){
    int v = u - 1440;
    int tb = v/144, tp = v - tb*144;
    int b0 = tb*32, p0 = tp*64;
    #pragma unroll
    for (int pass = 0; pass < 2; ++pass){
      int vt = t + (pass << 7);
      int r = vt >> 3, c8 = (vt & 7)*8;
      const float* sp = x + (size_t)(b0 + r)*P_ + p0 + c8;
      float4 a = *reinterpret_cast<const float4*>(sp);
      float4 b = *reinterpret_cast<const float4*>(sp + 4);
      *reinterpret_cast<float4*>(&sm.t[r][c8]) = a;
      *reinterpret_cast<float4*>(&sm.t[r][c8+4]) = b;
      uint4 pk;
      pk.x = (unsigned)f2bf(a.x) | ((unsigned)f2bf(a.y) << 16);
      pk.y = (unsigned)f2bf(a.z) | ((unsigned)f2bf(a.w) << 16);
      pk.z = (unsigned)f2bf(b.x) | ((unsigned)f2bf(b.y) << 16);
      pk.w = (unsigned)f2bf(b.z) | ((unsigned)f2bf(b.w) << 16);
      *reinterpret_cast<uint4*>(xbp + (size_t)(b0 + r)*P_ + p0 + c8) = pk;
    }
    __syncthreads();
    #pragma unroll
    for (int pass = 0; pass < 2; ++pass){
      int vt = t + (pass << 7);
      int pc = vt >> 2, rb = (vt & 3)*8;
      uint4 pk;
      pk.x = (unsigned)f2bf(sm.t[rb+0][pc]) | ((unsigned)f2bf(sm.t[rb+1][pc]) << 16);
      pk.y = (unsigned)f2bf(sm.t[rb+2][pc]) | ((unsigned)f2bf(sm.t[rb+3][pc]) << 16);
      pk.z = (unsigned)f2bf(sm.t[rb+4][pc]) | ((unsigned)f2bf(sm.t[rb+5][pc]) << 16);
      pk.w = (unsigned)f2bf(sm.t[rb+6][pc]) | ((unsigned)f2bf(sm.t[rb+7][pc]) << 16);
      *reinterpret_cast<uint4*>(xpb + (size_t)(p0 + pc)*B_ + b0 + rb) = pk;
    }
  } else if (u < 2700){
    bij[(u - 2592)*128 + t] = 0.f;
  } else if (u < 3020){
    sA[(u - 2700)*128 + t] = 0.f;
  } else {
    for (int z = t; z < 4128; z += 128) bar[z] = 0;
  }
}

// ---------------------------------------------------------------------------
// Fence-free monotonic grid barrier (R4-proven), 1280 arrivals:
// 64 leaves x 20 -> root(64) -> 64 padded release words. RELAXED agent
// atomics only; __syncthreads before arrival drains vmcnt.
// bar: leaf li @ [li*32]; rel li @ [2048+li*32]; root @ [4096]; cflag @ [4100].
__device__ inline void gbar(int* bar, int bid, int ph){
  __syncthreads();
  if (threadIdx.x == 0){
    int li = bid & 63;
    if (__hip_atomic_fetch_add(bar + li*32, 1, __ATOMIC_RELAXED,
                               __HIP_MEMORY_SCOPE_AGENT) == ph*20 - 1){
      if (__hip_atomic_fetch_add(bar + 4096, 1, __ATOMIC_RELAXED,
                                 __HIP_MEMORY_SCOPE_AGENT) == ph*64 - 1){
        #pragma unroll
        for (int z = 0; z < 64; ++z)
          __hip_atomic_store(bar + 2048 + z*32, ph, __ATOMIC_RELAXED,
                             __HIP_MEMORY_SCOPE_AGENT);
      }
    }
    while (__hip_atomic_load(bar + 2048 + li*32, __ATOMIC_RELAXED,
                             __HIP_MEMORY_SCOPE_AGENT) < ph)
      __builtin_amdgcn_s_sleep(4);
  }
  __syncthreads();
}

// ---------------------------------------------------------------------------
union LdsU {
  struct { float c[720]; u16 Bt[16][592]; } S;   // 2880 + 18944 = 21824 B
  u16 vl[32][264];                               // 16896 B
};

// C-sub-phase + flag (replaces 2 full barriers): 9 blocks softmax bij once,
// write cT (MALL stores), bump cflag; ALL blocks spin cflag >= target.
// Spin cost hides under the Wt prefetch issued before the preceding gbar.
__device__ inline void phase_C(int t, int bid,
    const float* __restrict__ bij, float* __restrict__ cT,
    int* __restrict__ bar, int target)
{
  if (bid < 9){
    int j = bid*128 + t;
    const float* br = bij + (size_t)j*BIJS;
    f4v a; f4v b4; float2 c2;
    asm volatile(
      "global_load_dwordx4 %0, %3, off sc0 sc1\n\t"
      "global_load_dwordx4 %1, %3, off offset:16 sc0 sc1\n\t"
      "global_load_dwordx2 %2, %3, off offset:32 sc0 sc1\n\t"
      "s_waitcnt vmcnt(0)"
      : "=&v"(a), "=&v"(b4), "=&v"(c2)
      : "v"(br) : "memory");
    float l[10] = {a[0],a[1],a[2],a[3],b4[0],b4[1],b4[2],b4[3],c2.x,c2.y};
    float mx = l[0];
    #pragma unroll
    for (int k = 1; k < 10; ++k) mx = fmaxf(mx, l[k]);
    float e[10]; float se = 0.f;
    #pragma unroll
    for (int k = 0; k < 10; ++k){ e[k] = __expf(l[k]-mx); se += e[k]; }
    float inv = 1.0f / se;
    #pragma unroll
    for (int k = 0; k < 10; ++k) ast1(&cT[k*I_ + j], e[k]*inv);
    __syncthreads();                       // drain cT stores, then flag
    if (t == 0)
      __hip_atomic_fetch_add(bar + 4100, 1, __ATOMIC_RELAXED,
                             __HIP_MEMORY_SCOPE_AGENT);
  }
  if (t == 0){
    while (__hip_atomic_load(bar + 4100, __ATOMIC_RELAXED,
                             __HIP_MEMORY_SCOPE_AGENT) < target)
      __builtin_amdgcn_s_sleep(2);
  }
  __syncthreads();
}

// ---------------------------------------------------------------------------
// S phase (R4-proven body; Wt tile passed in pre-loaded): kc in [0,16),
// 576-wide K-chunk, split-K atomics into s_cur (16 contenders/address).
__device__ inline void phase_S(int t, int bid, int kc, int n, int bx2,
    const u16* __restrict__ xbp, const uint4* wpre,
    const float* __restrict__ cT, float* __restrict__ s_cur,
    float* __restrict__ s_zero, LdsU* lds)
{
  if (s_zero && t < 32) ast1(&s_zero[bid*32 + t], 0.f);
  int i0 = (kc & 1)*576;

  // stage c slice (576 contiguous fp32) into swizzled LDS
  const float* cp = cT + (size_t)n*I_ + i0;
  {
    float4 v = *reinterpret_cast<const float4*>(cp + 4*t);
    int d = CIX(4*t);
    lds->S.c[d] = v.x; lds->S.c[d+1] = v.y; lds->S.c[d+2] = v.z; lds->S.c[d+3] = v.w;
    if (t < 16){
      float4 w = *reinterpret_cast<const float4*>(cp + 512 + 4*t);
      int d2 = CIX(512 + 4*t);
      lds->S.c[d2] = w.x; lds->S.c[d2+1] = w.y; lds->S.c[d2+2] = w.z; lds->S.c[d2+3] = w.w;
    }
  }
  __syncthreads();

  // Bt = bf16(Wt * c) from the pre-loaded wpre tile
  #pragma unroll
  for (int s9 = 0; s9 < 9; ++s9){
    int uu = t + s9*128;
    int r = uu / 72, m = uu - r*72;
    uint4 w = wpre[s9];
    const float* cc = &lds->S.c[10*m];
    float2 ca = *reinterpret_cast<const float2*>(cc);
    float2 cb = *reinterpret_cast<const float2*>(cc + 2);
    float2 cd = *reinterpret_cast<const float2*>(cc + 4);
    float2 ce = *reinterpret_cast<const float2*>(cc + 6);
    uint4 rr;
    rr.x = (unsigned)f2bf(bf2f(w.x & 0xffff)*ca.x) | ((unsigned)f2bf(bf2f(w.x >> 16)*ca.y) << 16);
    rr.y = (unsigned)f2bf(bf2f(w.y & 0xffff)*cb.x) | ((unsigned)f2bf(bf2f(w.y >> 16)*cb.y) << 16);
    rr.z = (unsigned)f2bf(bf2f(w.z & 0xffff)*cd.x) | ((unsigned)f2bf(bf2f(w.z >> 16)*cd.y) << 16);
    rr.w = (unsigned)f2bf(bf2f(w.w & 0xffff)*ce.x) | ((unsigned)f2bf(bf2f(w.w >> 16)*ce.y) << 16);
    *reinterpret_cast<uint4*>(&lds->S.Bt[r][m*8]) = rr;
  }
  __syncthreads();

  int wid = t >> 6, l = t & 63, lo = l & 15, quad = l >> 4;
  int b0 = bx2*32 + wid*16;
  const s8v* ap = reinterpret_cast<const s8v*>(xbp + (size_t)(b0 + lo)*P_ + kc*576 + quad*8);
  f4v acc0 = {0.f,0.f,0.f,0.f}, acc1 = {0.f,0.f,0.f,0.f};
  #pragma unroll
  for (int s = 0; s < 9; ++s){
    s8v a0 = ap[8*s];
    s8v b0v = *reinterpret_cast<const s8v*>(&lds->S.Bt[lo][quad*8 + 64*s]);
    s8v a1 = ap[8*s + 4];
    s8v b1v = *reinterpret_cast<const s8v*>(&lds->S.Bt[lo][quad*8 + 64*s + 32]);
    acc0 = __builtin_amdgcn_mfma_f32_16x16x32_bf16(a0, b0v, acc0, 0, 0, 0);
    acc1 = __builtin_amdgcn_mfma_f32_16x16x32_bf16(a1, b1v, acc1, 0, 0, 0);
  }
  f4v acc = acc0 + acc1;
  int r0 = quad << 2;
  #pragma unroll
  for (int r = 0; r < 4; ++r)
    atomicAdd(&s_cur[(size_t)(b0 + r0 + r)*NO_ + n*16 + lo], acc[r]);
}

// ---------------------------------------------------------------------------
// G phase (R4-proven): per-block squash of s into LDS vl, MFMA over b,
// Wt-weight + 16-lane o-reduce, atomicAdd bij. u-map swizzled by 139.
__device__ inline void phase_G(int t, int bid,
    const u16* __restrict__ xpb, const float* __restrict__ s,
    const u16* __restrict__ Wt, float* __restrict__ bij, LdsU* lds)
{
  int qp = bid >> 8;                    // 0..4
  #pragma unroll
  for (int h = 0; h < 2; ++h){
    int b = t + (h << 7);
    #pragma unroll
    for (int nn = 0; nn < 2; ++nn){
      const float* sr = s + (size_t)b*NO_ + (qp*2 + nn)*16;
      float4 s0 = *reinterpret_cast<const float4*>(sr);
      float4 s1 = *reinterpret_cast<const float4*>(sr + 4);
      float4 s2 = *reinterpret_cast<const float4*>(sr + 8);
      float4 s3 = *reinterpret_cast<const float4*>(sr + 12);
      float sq = s0.x*s0.x+s0.y*s0.y+s0.z*s0.z+s0.w*s0.w
               + s1.x*s1.x+s1.y*s1.y+s1.z*s1.z+s1.w*s1.w
               + s2.x*s2.x+s2.y*s2.y+s2.z*s2.z+s2.w*s2.w
               + s3.x*s3.x+s3.y*s3.y+s3.z*s3.z+s3.w*s3.w;
      float scale = sqrtf(sq) / (1.0f + sq);
      float sv[16] = {s0.x,s0.y,s0.z,s0.w,s1.x,s1.y,s1.z,s1.w,
                      s2.x,s2.y,s2.z,s2.w,s3.x,s3.y,s3.z,s3.w};
      #pragma unroll
      for (int o = 0; o < 16; ++o)
        lds->vl[nn*16 + o][b] = f2bf(sv[o] * scale);
    }
  }
  __syncthreads();

  int wv = t >> 6, l = t & 63, lo = l & 15, quad = l >> 4;
  int idx = (139*(bid & 255)) & 255;
  for (int u = idx*2 + wv; u < 576; u += 512){
    int p0 = u << 4;
    const s8v* ap = reinterpret_cast<const s8v*>(xpb + (size_t)(p0 + lo)*B_ + quad*8);
    f4v acc0 = {0.f,0.f,0.f,0.f}, acc1 = {0.f,0.f,0.f,0.f};
    #pragma unroll
    for (int st = 0; st < 8; ++st){
      s8v a  = ap[4*st];
      s8v b0 = *reinterpret_cast<const s8v*>(&lds->vl[lo]     [st*32 + quad*8]);
      s8v b1 = *reinterpret_cast<const s8v*>(&lds->vl[16 + lo][st*32 + quad*8]);
      acc0 = __builtin_amdgcn_mfma_f32_16x16x32_bf16(a, b0, acc0, 0, 0, 0);
      acc1 = __builtin_amdgcn_mfma_f32_16x16x32_bf16(a, b1, acc1, 0, 0, 0);
    }
    int ib = p0 % 1152;                 // p-tile never spans k (1152%16==0)
    #pragma unroll
    for (int sb = 0; sb < 2; ++sb){
      f4v acc = sb ? acc1 : acc0;
      int n = qp*2 + sb;
      const u16* wp = Wt + (size_t)(n*16 + lo)*P_ + p0 + (quad << 2);
      ushort4 w4 = *reinterpret_cast<const ushort4*>(wp);
      float v0 = acc[0]*bf2f(w4.x), v1 = acc[1]*bf2f(w4.y);
      float v2 = acc[2]*bf2f(w4.z), v3 = acc[3]*bf2f(w4.w);
      #pragma unroll
      for (int m = 8; m >= 1; m >>= 1){
        v0 += __shfl_xor(v0, m, 16);
        v1 += __shfl_xor(v1, m, 16);
        v2 += __shfl_xor(v2, m, 16);
        v3 += __shfl_xor(v3, m, 16);
      }
      if (lo == 0){
        int i = ib + (quad << 2);
        atomicAdd(&bij[(size_t)(i+0)*BIJS + n], v0 * (1.f/256.f));
        atomicAdd(&bij[(size_t)(i+1)*BIJS + n], v1 * (1.f/256.f));
        atomicAdd(&bij[(size_t)(i+2)*BIJS + n], v2 * (1.f/256.f));
        atomicAdd(&bij[(size_t)(i+3)*BIJS + n], v3 * (1.f/256.f));
      }
    }
  }
}

__global__ __launch_bounds__(128, 3) void k_route(
    const u16* __restrict__ xbp, const u16* __restrict__ xpb,
    const u16* __restrict__ Wt, float* __restrict__ bij,
    float* __restrict__ cTa, float* __restrict__ cTb,
    float* __restrict__ sA, float* __restrict__ sB,
    float* __restrict__ out, int* __restrict__ bar)
{
  __shared__ LdsU lds;
  int t = threadIdx.x, bid = blockIdx.x;
  int kc = (bid & 7)*2 + ((bid >> 3) & 1);    // S-decomposition (R4)
  int g2 = bid >> 4;
  int n = g2 % 10, bx2 = g2 / 10;

  // ---- iter0 S: c == 0.1 uniform -> s = 0.1*(x . Wt^T), raw Wt B-frags,
  // scale in fp32 epilogue. Zeroes sB (MALL-visible).
  {
    if (t < 32) ast1(&sB[bid*32 + t], 0.f);
    int wid = t >> 6, l = t & 63, lo = l & 15, quad = l >> 4;
    int b0 = bx2*32 + wid*16;
    const s8v* ap = reinterpret_cast<const s8v*>(xbp + (size_t)(b0 + lo)*P_ + kc*576 + quad*8);
    const s8v* bp = reinterpret_cast<const s8v*>(Wt  + (size_t)(n*16 + lo)*P_ + kc*576 + quad*8);
    f4v acc0 = {0.f,0.f,0.f,0.f}, acc1 = {0.f,0.f,0.f,0.f};
    #pragma unroll
    for (int s = 0; s < 9; ++s){
      acc0 = __builtin_amdgcn_mfma_f32_16x16x32_bf16(ap[8*s],     bp[8*s],     acc0, 0, 0, 0);
      acc1 = __builtin_amdgcn_mfma_f32_16x16x32_bf16(ap[8*s + 4], bp[8*s + 4], acc1, 0, 0, 0);
    }
    f4v acc = acc0 + acc1;
    int r0 = quad << 2;
    #pragma unroll
    for (int r = 0; r < 4; ++r)
      atomicAdd(&sA[(size_t)(b0 + r0 + r)*NO_ + n*16 + lo], acc[r] * 0.1f);
  }
  gbar(bar, bid, 1);

  phase_G(t, bid, xpb, sA, Wt, bij, &lds);          // iter0 agreement
  // Prefetch the S-phase Wt tile BEFORE the barrier: latency hides under the
  // barrier wait + C flag-spin; same (kc,n) tile serves BOTH S1 and S2.
  uint4 wpre[9];
  #pragma unroll
  for (int s9 = 0; s9 < 9; ++s9){
    int uu = t + s9*128;
    int r = uu / 72, m = uu - r*72;
    wpre[s9] = *reinterpret_cast<const uint4*>(
        Wt + (size_t)(n*16 + r)*P_ + kc*576 + m*8);
  }
  gbar(bar, bid, 2);

  phase_C(t, bid, bij, cTa, bar, 9);                // softmax -> cTa (flag)
  phase_S(t, bid, kc, n, bx2, xbp, wpre, cTa, sB, sA, &lds);  // iter1 -> sB
  gbar(bar, bid, 3);

  phase_G(t, bid, xpb, sB, Wt, bij, &lds);          // iter1 agreement
  gbar(bar, bid, 4);

  phase_C(t, bid, bij, cTb, bar, 18);               // softmax -> cTb (flag)
  phase_S(t, bid, kc, n, bx2, xbp, wpre, cTb, sA, nullptr, &lds); // iter2 -> sA
  gbar(bar, bid, 5);

  // ---- final squash -> out (2560 rows of 16; first 320 blocks)
  if (bid < 320){
    int o = t & 15, rl = t >> 4;
    int rowid = bid*8 + rl;               // b*10+n
    int b = rowid / 10, nn = rowid - b*10;
    size_t idx = (size_t)b*NO_ + nn*16 + o;
    float sv = ald1(&sA[idx]);
    float sq = sv * sv;
    #pragma unroll
    for (int m = 8; m >= 1; m >>= 1) sq += __shfl_xor(sq, m, 16);
    out[idx] = sv * sqrtf(sq) / (1.0f + sq);
  }
}

// ---------------------------------------------------------------------------
extern "C" void kernel_launch(void* const* d_in, const int* in_sizes, int n_in,
                              void* d_out, int out_size, void* d_ws, size_t ws_size,
                              hipStream_t stream){
  (void)in_sizes; (void)n_in; (void)out_size; (void)ws_size;
  const float* x = (const float*)d_in[0];   // (256, 8, 1152)
  const float* W = (const float*)d_in[1];   // (1, 1152, 10, 16, 8)
  float* out = (float*)d_out;               // (256, 10, 16, 1) fp32

  float* sA  = (float*)d_ws;                // 40960 fp32
  float* sB  = sA + 40960;                  // 40960
  float* bij = sB + 40960;                  // 13824 (1152 x 12)
  float* cTa = bij + 13824;                 // 11520 (10 x 1152)
  float* cTb = cTa + 11520;                 // 11520
  u16* xbp = (u16*)(cTb + 11520);           // 2359296 bf16
  u16* xpb = xbp + 2359296;                 // 2359296
  u16* Wt  = xpb + 2359296;                 // 1474560
  int* bar = (int*)(Wt + 1474560);          // 4128 ints (barrier + cflag)

  k_prep <<<3021, 128, 0, stream>>>(x, W, xbp, xpb, Wt, bij, sA, bar);
  k_route<<<NBLK, 128, 0, stream>>>(xbp, xpb, Wt, bij, cTa, cTb, sA, sB, out, bar);
}

// Round 8
// 140.623 us; speedup vs baseline: 1.5777x; 1.0799x over previous
//
#include <hip/hip_runtime.h>

#define B_   256
#define I_   1152
#define N_   10
#define P_   9216      // 8 * 1152
#define NO_  160       // 10 * 16
#define BIJS 12        // padded bij row stride (floats) -> 48B rows, 16B aligned
#define NBLK 1280

typedef unsigned short u16;
typedef short s8v __attribute__((ext_vector_type(8)));
typedef float f4v __attribute__((ext_vector_type(4)));

__device__ inline float bf2f(u16 u){
  unsigned v = ((unsigned)u) << 16; float f; __builtin_memcpy(&f, &v, 4); return f;
}
__device__ inline u16 f2bf(float f){
  unsigned b; __builtin_memcpy(&b, &f, 4);
  b += 0x7fffu + ((b >> 16) & 1u);   // RNE
  return (u16)(b >> 16);
}
// MALL-coherent scalar accessors (bypass L1/L2; atomic-produced data lives at MALL)
__device__ inline float ald1(const float* p){
  unsigned u = __hip_atomic_load((const unsigned*)p,
      __ATOMIC_RELAXED, __HIP_MEMORY_SCOPE_AGENT);
  float f; __builtin_memcpy(&f, &u, 4); return f;
}
__device__ inline void ast1(float* p, float v){
  unsigned u; __builtin_memcpy(&u, &v, 4);
  __hip_atomic_store((unsigned*)p, u, __ATOMIC_RELAXED, __HIP_MEMORY_SCOPE_AGENT);
}

// c LDS swizzle: element j stored at CIX(j); reader at 10m..10m+7 gets j=8m..8m+7
#define CIX(j) ((j) + (((j) >> 3) << 1))

// ---------------------------------------------------------------------------
// k_prep (R4-proven): 3021 blocks x 128.
//  [0,1440):   W -> Wt bf16 (LDS transpose, uint4 stores)
//  [1440,2592): x -> xbp + xpb (LDS transpose, uint4 stores)
//  [2592,2700): zero bij (13824 fl, stride-12 rows)
//  [2700,3020): zero sA
//  3020:        zero bar (4128 ints; includes cflag)
__global__ __launch_bounds__(128) void k_prep(
    const float* __restrict__ x, const float* __restrict__ W,
    u16* __restrict__ xbp, u16* __restrict__ xpb, u16* __restrict__ Wt,
    float* __restrict__ bij, float* __restrict__ sA, int* __restrict__ bar){
  __shared__ union { u16 w[8][136]; float t[32][68]; } sm;
  int t = threadIdx.x, u = blockIdx.x;
  if (u < 1440){
    int q = u/9, ch = u - q*9;
    int n = q >> 4, o = q & 15;
    int i = ch*128 + t;
    const float* src = W + (size_t)i*1280 + n*128 + o*8;
    float4 a = *reinterpret_cast<const float4*>(src);
    float4 b = *reinterpret_cast<const float4*>(src + 4);
    float vv[8] = {a.x,a.y,a.z,a.w,b.x,b.y,b.z,b.w};
    #pragma unroll
    for (int k = 0; k < 8; ++k) sm.w[k][t] = f2bf(vv[k] * 0.03f);
    __syncthreads();
    int k = t >> 4, seg = t & 15;
    uint4 val = *reinterpret_cast<const uint4*>(&sm.w[k][seg*8]);
    *reinterpret_cast<uint4*>(Wt + (size_t)q*P_ + (size_t)k*I_ + ch*128 + seg*8) = val;
  } else if (u < 2592){
    int v = u - 1440;
    int tb = v/144, tp = v - tb*144;
    int b0 = tb*32, p0 = tp*64;
    #pragma unroll
    for (int pass = 0; pass < 2; ++pass){
      int vt = t + (pass << 7);
      int r = vt >> 3, c8 = (vt & 7)*8;
      const float* sp = x + (size_t)(b0 + r)*P_ + p0 + c8;
      float4 a = *reinterpret_cast<const float4*>(sp);
      float4 b = *reinterpret_cast<const float4*>(sp + 4);
      *reinterpret_cast<float4*>(&sm.t[r][c8]) = a;
      *reinterpret_cast<float4*>(&sm.t[r][c8+4]) = b;
      uint4 pk;
      pk.x = (unsigned)f2bf(a.x) | ((unsigned)f2bf(a.y) << 16);
      pk.y = (unsigned)f2bf(a.z) | ((unsigned)f2bf(a.w) << 16);
      pk.z = (unsigned)f2bf(b.x) | ((unsigned)f2bf(b.y) << 16);
      pk.w = (unsigned)f2bf(b.z) | ((unsigned)f2bf(b.w) << 16);
      *reinterpret_cast<uint4*>(xbp + (size_t)(b0 + r)*P_ + p0 + c8) = pk;
    }
    __syncthreads();
    #pragma unroll
    for (int pass = 0; pass < 2; ++pass){
      int vt = t + (pass << 7);
      int pc = vt >> 2, rb = (vt & 3)*8;
      uint4 pk;
      pk.x = (unsigned)f2bf(sm.t[rb+0][pc]) | ((unsigned)f2bf(sm.t[rb+1][pc]) << 16);
      pk.y = (unsigned)f2bf(sm.t[rb+2][pc]) | ((unsigned)f2bf(sm.t[rb+3][pc]) << 16);
      pk.z = (unsigned)f2bf(sm.t[rb+4][pc]) | ((unsigned)f2bf(sm.t[rb+5][pc]) << 16);
      pk.w = (unsigned)f2bf(sm.t[rb+6][pc]) | ((unsigned)f2bf(sm.t[rb+7][pc]) << 16);
      *reinterpret_cast<uint4*>(xpb + (size_t)(p0 + pc)*B_ + b0 + rb) = pk;
    }
  } else if (u < 2700){
    bij[(u - 2592)*128 + t] = 0.f;
  } else if (u < 3020){
    sA[(u - 2700)*128 + t] = 0.f;
  } else {
    for (int z = t; z < 4128; z += 128) bar[z] = 0;
  }
}

// ---------------------------------------------------------------------------
// Fence-free monotonic grid barrier (R4-proven), 1280 arrivals:
// 64 leaves x 20 -> root(64) -> 64 padded release words. RELAXED agent
// atomics only; __syncthreads before arrival drains vmcnt.
// bar: leaf li @ [li*32]; rel li @ [2048+li*32]; root @ [4096]; cflag @ [4100].
__device__ inline void gbar(int* bar, int bid, int ph){
  __syncthreads();
  if (threadIdx.x == 0){
    int li = bid & 63;
    if (__hip_atomic_fetch_add(bar + li*32, 1, __ATOMIC_RELAXED,
                               __HIP_MEMORY_SCOPE_AGENT) == ph*20 - 1){
      if (__hip_atomic_fetch_add(bar + 4096, 1, __ATOMIC_RELAXED,
                                 __HIP_MEMORY_SCOPE_AGENT) == ph*64 - 1){
        #pragma unroll
        for (int z = 0; z < 64; ++z)
          __hip_atomic_store(bar + 2048 + z*32, ph, __ATOMIC_RELAXED,
                             __HIP_MEMORY_SCOPE_AGENT);
      }
    }
    while (__hip_atomic_load(bar + 2048 + li*32, __ATOMIC_RELAXED,
                             __HIP_MEMORY_SCOPE_AGENT) < ph)
      __builtin_amdgcn_s_sleep(4);
  }
  __syncthreads();
}

// ---------------------------------------------------------------------------
union LdsU {
  struct { float c[720]; u16 Bt[16][592]; } S;   // 2880 + 18944 = 21824 B
  u16 vl[32][264];                               // 16896 B
};

// C-sub-phase + flag (replaces 2 full barriers): 9 blocks softmax bij once,
// write cT (MALL stores), bump cflag; ALL blocks spin cflag >= target.
__device__ inline void phase_C(int t, int bid,
    const float* __restrict__ bij, float* __restrict__ cT,
    int* __restrict__ bar, int target)
{
  if (bid < 9){
    int j = bid*128 + t;
    const float* br = bij + (size_t)j*BIJS;
    f4v a; f4v b4; float2 c2;
    asm volatile(
      "global_load_dwordx4 %0, %3, off sc0 sc1\n\t"
      "global_load_dwordx4 %1, %3, off offset:16 sc0 sc1\n\t"
      "global_load_dwordx2 %2, %3, off offset:32 sc0 sc1\n\t"
      "s_waitcnt vmcnt(0)"
      : "=&v"(a), "=&v"(b4), "=&v"(c2)
      : "v"(br) : "memory");
    float l[10] = {a[0],a[1],a[2],a[3],b4[0],b4[1],b4[2],b4[3],c2.x,c2.y};
    float mx = l[0];
    #pragma unroll
    for (int k = 1; k < 10; ++k) mx = fmaxf(mx, l[k]);
    float e[10]; float se = 0.f;
    #pragma unroll
    for (int k = 0; k < 10; ++k){ e[k] = __expf(l[k]-mx); se += e[k]; }
    float inv = 1.0f / se;
    #pragma unroll
    for (int k = 0; k < 10; ++k) ast1(&cT[k*I_ + j], e[k]*inv);
    __syncthreads();                       // drain cT stores, then flag
    if (t == 0)
      __hip_atomic_fetch_add(bar + 4100, 1, __ATOMIC_RELAXED,
                             __HIP_MEMORY_SCOPE_AGENT);
  }
  if (t == 0){
    while (__hip_atomic_load(bar + 4100, __ATOMIC_RELAXED,
                             __HIP_MEMORY_SCOPE_AGENT) < target)
      __builtin_amdgcn_s_sleep(2);
  }
  __syncthreads();
}

// ---------------------------------------------------------------------------
// S phase (exact R4 body — Wt loaded IN-PHASE; R7's cross-barrier prefetch
// spilled to scratch: +30 MB fetch, +40 MB write, +11 µs). kc in [0,16),
// 576-wide K-chunk, split-K atomics into s_cur (16 contenders/address).
__device__ inline void phase_S(int t, int bid, int kc, int n, int bx2,
    const u16* __restrict__ xbp, const u16* __restrict__ Wt,
    const float* __restrict__ cT, float* __restrict__ s_cur,
    float* __restrict__ s_zero, LdsU* lds)
{
  if (s_zero && t < 32) ast1(&s_zero[bid*32 + t], 0.f);
  int i0 = (kc & 1)*576;

  // stage c slice (576 contiguous fp32) into swizzled LDS
  const float* cp = cT + (size_t)n*I_ + i0;
  {
    float4 v = *reinterpret_cast<const float4*>(cp + 4*t);
    int d = CIX(4*t);
    lds->S.c[d] = v.x; lds->S.c[d+1] = v.y; lds->S.c[d+2] = v.z; lds->S.c[d+3] = v.w;
    if (t < 16){
      float4 w = *reinterpret_cast<const float4*>(cp + 512 + 4*t);
      int d2 = CIX(512 + 4*t);
      lds->S.c[d2] = w.x; lds->S.c[d2+1] = w.y; lds->S.c[d2+2] = w.z; lds->S.c[d2+3] = w.w;
    }
  }
  __syncthreads();

  // Bt = bf16(Wt * c); Wt tile is L2-resident (XCD-affine kc)
  #pragma unroll
  for (int s9 = 0; s9 < 9; ++s9){
    int uu = t + s9*128;
    int r = uu / 72, m = uu - r*72;
    uint4 w = *reinterpret_cast<const uint4*>(Wt + (size_t)(n*16 + r)*P_ + kc*576 + m*8);
    const float* cc = &lds->S.c[10*m];
    float2 ca = *reinterpret_cast<const float2*>(cc);
    float2 cb = *reinterpret_cast<const float2*>(cc + 2);
    float2 cd = *reinterpret_cast<const float2*>(cc + 4);
    float2 ce = *reinterpret_cast<const float2*>(cc + 6);
    uint4 rr;
    rr.x = (unsigned)f2bf(bf2f(w.x & 0xffff)*ca.x) | ((unsigned)f2bf(bf2f(w.x >> 16)*ca.y) << 16);
    rr.y = (unsigned)f2bf(bf2f(w.y & 0xffff)*cb.x) | ((unsigned)f2bf(bf2f(w.y >> 16)*cb.y) << 16);
    rr.z = (unsigned)f2bf(bf2f(w.z & 0xffff)*cd.x) | ((unsigned)f2bf(bf2f(w.z >> 16)*cd.y) << 16);
    rr.w = (unsigned)f2bf(bf2f(w.w & 0xffff)*ce.x) | ((unsigned)f2bf(bf2f(w.w >> 16)*ce.y) << 16);
    *reinterpret_cast<uint4*>(&lds->S.Bt[r][m*8]) = rr;
  }
  __syncthreads();

  int wid = t >> 6, l = t & 63, lo = l & 15, quad = l >> 4;
  int b0 = bx2*32 + wid*16;
  const s8v* ap = reinterpret_cast<const s8v*>(xbp + (size_t)(b0 + lo)*P_ + kc*576 + quad*8);
  f4v acc0 = {0.f,0.f,0.f,0.f}, acc1 = {0.f,0.f,0.f,0.f};
  #pragma unroll
  for (int s = 0; s < 9; ++s){
    s8v a0 = ap[8*s];
    s8v b0v = *reinterpret_cast<const s8v*>(&lds->S.Bt[lo][quad*8 + 64*s]);
    s8v a1 = ap[8*s + 4];
    s8v b1v = *reinterpret_cast<const s8v*>(&lds->S.Bt[lo][quad*8 + 64*s + 32]);
    acc0 = __builtin_amdgcn_mfma_f32_16x16x32_bf16(a0, b0v, acc0, 0, 0, 0);
    acc1 = __builtin_amdgcn_mfma_f32_16x16x32_bf16(a1, b1v, acc1, 0, 0, 0);
  }
  f4v acc = acc0 + acc1;
  int r0 = quad << 2;
  #pragma unroll
  for (int r = 0; r < 4; ++r)
    atomicAdd(&s_cur[(size_t)(b0 + r0 + r)*NO_ + n*16 + lo], acc[r]);
}

// ---------------------------------------------------------------------------
// G phase (R4-proven): per-block squash of s into LDS vl, MFMA over b,
// Wt-weight + 16-lane o-reduce, atomicAdd bij. u-map swizzled by 139.
__device__ inline void phase_G(int t, int bid,
    const u16* __restrict__ xpb, const float* __restrict__ s,
    const u16* __restrict__ Wt, float* __restrict__ bij, LdsU* lds)
{
  int qp = bid >> 8;                    // 0..4
  #pragma unroll
  for (int h = 0; h < 2; ++h){
    int b = t + (h << 7);
    #pragma unroll
    for (int nn = 0; nn < 2; ++nn){
      const float* sr = s + (size_t)b*NO_ + (qp*2 + nn)*16;
      float4 s0 = *reinterpret_cast<const float4*>(sr);
      float4 s1 = *reinterpret_cast<const float4*>(sr + 4);
      float4 s2 = *reinterpret_cast<const float4*>(sr + 8);
      float4 s3 = *reinterpret_cast<const float4*>(sr + 12);
      float sq = s0.x*s0.x+s0.y*s0.y+s0.z*s0.z+s0.w*s0.w
               + s1.x*s1.x+s1.y*s1.y+s1.z*s1.z+s1.w*s1.w
               + s2.x*s2.x+s2.y*s2.y+s2.z*s2.z+s2.w*s2.w
               + s3.x*s3.x+s3.y*s3.y+s3.z*s3.z+s3.w*s3.w;
      float scale = sqrtf(sq) / (1.0f + sq);
      float sv[16] = {s0.x,s0.y,s0.z,s0.w,s1.x,s1.y,s1.z,s1.w,
                      s2.x,s2.y,s2.z,s2.w,s3.x,s3.y,s3.z,s3.w};
      #pragma unroll
      for (int o = 0; o < 16; ++o)
        lds->vl[nn*16 + o][b] = f2bf(sv[o] * scale);
    }
  }
  __syncthreads();

  int wv = t >> 6, l = t & 63, lo = l & 15, quad = l >> 4;
  int idx = (139*(bid & 255)) & 255;
  for (int u = idx*2 + wv; u < 576; u += 512){
    int p0 = u << 4;
    const s8v* ap = reinterpret_cast<const s8v*>(xpb + (size_t)(p0 + lo)*B_ + quad*8);
    f4v acc0 = {0.f,0.f,0.f,0.f}, acc1 = {0.f,0.f,0.f,0.f};
    #pragma unroll
    for (int st = 0; st < 8; ++st){
      s8v a  = ap[4*st];
      s8v b0 = *reinterpret_cast<const s8v*>(&lds->vl[lo]     [st*32 + quad*8]);
      s8v b1 = *reinterpret_cast<const s8v*>(&lds->vl[16 + lo][st*32 + quad*8]);
      acc0 = __builtin_amdgcn_mfma_f32_16x16x32_bf16(a, b0, acc0, 0, 0, 0);
      acc1 = __builtin_amdgcn_mfma_f32_16x16x32_bf16(a, b1, acc1, 0, 0, 0);
    }
    int ib = p0 % 1152;                 // p-tile never spans k (1152%16==0)
    #pragma unroll
    for (int sb = 0; sb < 2; ++sb){
      f4v acc = sb ? acc1 : acc0;
      int n = qp*2 + sb;
      const u16* wp = Wt + (size_t)(n*16 + lo)*P_ + p0 + (quad << 2);
      ushort4 w4 = *reinterpret_cast<const ushort4*>(wp);
      float v0 = acc[0]*bf2f(w4.x), v1 = acc[1]*bf2f(w4.y);
      float v2 = acc[2]*bf2f(w4.z), v3 = acc[3]*bf2f(w4.w);
      #pragma unroll
      for (int m = 8; m >= 1; m >>= 1){
        v0 += __shfl_xor(v0, m, 16);
        v1 += __shfl_xor(v1, m, 16);
        v2 += __shfl_xor(v2, m, 16);
        v3 += __shfl_xor(v3, m, 16);
      }
      if (lo == 0){
        int i = ib + (quad << 2);
        atomicAdd(&bij[(size_t)(i+0)*BIJS + n], v0 * (1.f/256.f));
        atomicAdd(&bij[(size_t)(i+1)*BIJS + n], v1 * (1.f/256.f));
        atomicAdd(&bij[(size_t)(i+2)*BIJS + n], v2 * (1.f/256.f));
        atomicAdd(&bij[(size_t)(i+3)*BIJS + n], v3 * (1.f/256.f));
      }
    }
  }
}

__global__ __launch_bounds__(128, 3) void k_route(
    const u16* __restrict__ xbp, const u16* __restrict__ xpb,
    const u16* __restrict__ Wt, float* __restrict__ bij,
    float* __restrict__ cTa, float* __restrict__ cTb,
    float* __restrict__ sA, float* __restrict__ sB,
    float* __restrict__ out, int* __restrict__ bar)
{
  __shared__ LdsU lds;
  int t = threadIdx.x, bid = blockIdx.x;
  int kc = (bid & 7)*2 + ((bid >> 3) & 1);    // S-decomposition (R4)
  int g2 = bid >> 4;
  int n = g2 % 10, bx2 = g2 / 10;

  // ---- iter0 S: c == 0.1 uniform -> s = 0.1*(x . Wt^T), raw Wt B-frags,
  // scale in fp32 epilogue. Zeroes sB (MALL-visible).
  {
    if (t < 32) ast1(&sB[bid*32 + t], 0.f);
    int wid = t >> 6, l = t & 63, lo = l & 15, quad = l >> 4;
    int b0 = bx2*32 + wid*16;
    const s8v* ap = reinterpret_cast<const s8v*>(xbp + (size_t)(b0 + lo)*P_ + kc*576 + quad*8);
    const s8v* bp = reinterpret_cast<const s8v*>(Wt  + (size_t)(n*16 + lo)*P_ + kc*576 + quad*8);
    f4v acc0 = {0.f,0.f,0.f,0.f}, acc1 = {0.f,0.f,0.f,0.f};
    #pragma unroll
    for (int s = 0; s < 9; ++s){
      acc0 = __builtin_amdgcn_mfma_f32_16x16x32_bf16(ap[8*s],     bp[8*s],     acc0, 0, 0, 0);
      acc1 = __builtin_amdgcn_mfma_f32_16x16x32_bf16(ap[8*s + 4], bp[8*s + 4], acc1, 0, 0, 0);
    }
    f4v acc = acc0 + acc1;
    int r0 = quad << 2;
    #pragma unroll
    for (int r = 0; r < 4; ++r)
      atomicAdd(&sA[(size_t)(b0 + r0 + r)*NO_ + n*16 + lo], acc[r] * 0.1f);
  }
  gbar(bar, bid, 1);

  phase_G(t, bid, xpb, sA, Wt, bij, &lds);          // iter0 agreement
  gbar(bar, bid, 2);

  phase_C(t, bid, bij, cTa, bar, 9);                // softmax -> cTa (flag)
  phase_S(t, bid, kc, n, bx2, xbp, Wt, cTa, sB, sA, &lds);  // iter1 -> sB
  gbar(bar, bid, 3);

  phase_G(t, bid, xpb, sB, Wt, bij, &lds);          // iter1 agreement
  gbar(bar, bid, 4);

  phase_C(t, bid, bij, cTb, bar, 18);               // softmax -> cTb (flag)
  phase_S(t, bid, kc, n, bx2, xbp, Wt, cTb, sA, nullptr, &lds); // iter2 -> sA
  gbar(bar, bid, 5);

  // ---- final squash -> out (2560 rows of 16; first 320 blocks)
  if (bid < 320){
    int o = t & 15, rl = t >> 4;
    int rowid = bid*8 + rl;               // b*10+n
    int b = rowid / 10, nn = rowid - b*10;
    size_t idx = (size_t)b*NO_ + nn*16 + o;
    float sv = ald1(&sA[idx]);
    float sq = sv * sv;
    #pragma unroll
    for (int m = 8; m >= 1; m >>= 1) sq += __shfl_xor(sq, m, 16);
    out[idx] = sv * sqrtf(sq) / (1.0f + sq);
  }
}

// ---------------------------------------------------------------------------
extern "C" void kernel_launch(void* const* d_in, const int* in_sizes, int n_in,
                              void* d_out, int out_size, void* d_ws, size_t ws_size,
                              hipStream_t stream){
  (void)in_sizes; (void)n_in; (void)out_size; (void)ws_size;
  const float* x = (const float*)d_in[0];   // (256, 8, 1152)
  const float* W = (const float*)d_in[1];   // (1, 1152, 10, 16, 8)
  float* out = (float*)d_out;               // (256, 10, 16, 1) fp32

  float* sA  = (float*)d_ws;                // 40960 fp32
  float* sB  = sA + 40960;                  // 40960
  float* bij = sB + 40960;                  // 13824 (1152 x 12)
  float* cTa = bij + 13824;                 // 11520 (10 x 1152)
  float* cTb = cTa + 11520;                 // 11520
  u16* xbp = (u16*)(cTb + 11520);           // 2359296 bf16
  u16* xpb = xbp + 2359296;                 // 2359296
  u16* Wt  = xpb + 2359296;                 // 1474560
  int* bar = (int*)(Wt + 1474560);          // 4128 ints (barrier + cflag)

  k_prep <<<3021, 128, 0, stream>>>(x, W, xbp, xpb, Wt, bij, sA, bar);
  k_route<<<NBLK, 128, 0, stream>>>(xbp, xpb, Wt, bij, cTa, cTb, sA, sB, out, bar);
}